// Round 7
// baseline (991.311 us; speedup 1.0000x reference)
//
#include <hip/hip_runtime.h>
#include <hip/hip_bf16.h>

#define NN 6000
#define NPAD 6016      // 94*64
#define DF 512
#define HID 256
#define NH 8
#define NC 32
#define FTOT 2048
#define MSTR 96        // u64 words per mask row
#define NJB (NPAD / 64)
#define L2E 1.4426950408889634f

using short8 = __attribute__((ext_vector_type(8))) short;
using f32x16 = __attribute__((ext_vector_type(16))) float;
using f32x4  = __attribute__((ext_vector_type(4))) float;

__device__ __forceinline__ unsigned short f2bf(float f) {
    unsigned int u = __float_as_uint(f);
    return (unsigned short)((u + 0x7fffu + ((u >> 16) & 1u)) >> 16);
}
__device__ __forceinline__ float bf2f(unsigned short s) {
    return __uint_as_float(((unsigned int)s) << 16);
}
// async global->LDS, 16B per lane (gemm_h only)
__device__ __forceinline__ void gl16(const void* g, void* l) {
    __builtin_amdgcn_global_load_lds(
        (const __attribute__((address_space(1))) unsigned int*)g,
        (__attribute__((address_space(3))) unsigned int*)l, 16, 0, 0);
}

// ---------------- prep kernels (verified r3/r4) ----------------

__global__ void pack_bits(const int* __restrict__ adj, unsigned char* __restrict__ maskb) {
    int row = blockIdx.y;
    int b = blockIdx.x * 256 + threadIdx.x;     // byte index 0..767
    if (b >= 768) return;
    int j0 = b * 8;
    unsigned int v = 0;
    if (j0 + 7 < NN) {
        const int4* p = (const int4*)(adj + (size_t)row * NN + j0);
        int4 a = p[0], c = p[1];
        v = (unsigned)((a.x>0) | ((a.y>0)<<1) | ((a.z>0)<<2) | ((a.w>0)<<3)
          | ((c.x>0)<<4) | ((c.y>0)<<5) | ((c.z>0)<<6) | ((c.w>0)<<7));
    }
    maskb[(size_t)row * 768 + b] = (unsigned char)v;
}

__global__ void cast_x4(const float* __restrict__ x, unsigned short* __restrict__ xb, int n4) {
    int i = blockIdx.x * 256 + threadIdx.x;
    if (i >= n4) return;
    float4 v = ((const float4*)x)[i];
    unsigned long long pk = (unsigned long long)f2bf(v.x)
        | ((unsigned long long)f2bf(v.y) << 16)
        | ((unsigned long long)f2bf(v.z) << 32)
        | ((unsigned long long)f2bf(v.w) << 48);
    ((unsigned long long*)xb)[i] = pk;
}

__global__ void wt_pack(const float* __restrict__ W0, unsigned short* __restrict__ Wt) {
    int fp = blockIdx.x;                 // h*256+f
    int h = fp >> 8, f = fp & 255;
    for (int k = threadIdx.x; k < DF; k += 256)
        Wt[(size_t)fp * DF + k] = f2bf(W0[(((size_t)h * DF + k) << 8) | f]);
}

__global__ void wct_pack(const float* __restrict__ Wc, unsigned short* __restrict__ Wct) {
    int c = blockIdx.x;
    for (int k = threadIdx.x; k < FTOT; k += 256)
        Wct[(size_t)c * FTOT + k] = f2bf(Wc[(size_t)k * NC + c]);
}

// ---------------- GEMM1 (verified r3): Ht[f][i] = sum_k X[i][k] W[k][f] ----------------
__global__ __launch_bounds__(256, 2) void gemm_h(const unsigned short* __restrict__ A,
                                                 const unsigned short* __restrict__ B,
                                                 unsigned short* __restrict__ Ht) {
    __shared__ __align__(16) unsigned short As[128 * 64];
    __shared__ __align__(16) unsigned short Bs[128 * 64];
    const int w = threadIdx.x >> 6, l = threadIdx.x & 63;
    const int lrow = l & 31, kh = l >> 5;
    const int wm = w >> 1, wn = w & 1;
    const int mbase = blockIdx.x * 128, nbase = blockIdx.y * 128;
    const int srcc = (l & 7) ^ (l >> 3);
    f32x16 acc[2][2];
#pragma unroll
    for (int i = 0; i < 2; ++i)
#pragma unroll
        for (int j = 0; j < 2; ++j) acc[i][j] = (f32x16)0.0f;

#pragma unroll 1
    for (int kb = 0; kb < DF / 64; ++kb) {
        __syncthreads();
#pragma unroll
        for (int q = 0; q < 4; ++q) {
            int c = q * 4 + w;
            int r = c * 8 + (l >> 3);
            int arow = mbase + r; if (arow > NN - 1) arow = NN - 1;
            gl16(A + (size_t)arow * DF + kb * 64 + srcc * 8, (char*)As + c * 1024);
            gl16(B + (size_t)(nbase + r) * DF + kb * 64 + srcc * 8, (char*)Bs + c * 1024);
        }
        __syncthreads();
#pragma unroll
        for (int kk = 0; kk < 4; ++kk) {
            short8 av[2], bv[2];
#pragma unroll
            for (int mt = 0; mt < 2; ++mt) {
                int r = wm * 64 + mt * 32 + lrow;
                av[mt] = *(const short8*)((const char*)As + r * 128 + ((((kk << 1) | kh) ^ (r & 7)) << 4));
            }
#pragma unroll
            for (int ft = 0; ft < 2; ++ft) {
                int r = wn * 64 + ft * 32 + lrow;
                bv[ft] = *(const short8*)((const char*)Bs + r * 128 + ((((kk << 1) | kh) ^ (r & 7)) << 4));
            }
#pragma unroll
            for (int mt = 0; mt < 2; ++mt)
#pragma unroll
                for (int ft = 0; ft < 2; ++ft)
                    acc[mt][ft] = __builtin_amdgcn_mfma_f32_32x32x16_bf16(av[mt], bv[ft], acc[mt][ft], 0, 0, 0);
        }
    }
#pragma unroll
    for (int mt = 0; mt < 2; ++mt)
#pragma unroll
        for (int ft = 0; ft < 2; ++ft) {
            size_t n = nbase + wn * 64 + ft * 32 + lrow;
#pragma unroll
            for (int g = 0; g < 4; ++g) {
                int m0 = mbase + wm * 64 + mt * 32 + (g << 3) + (kh << 2);
                unsigned long long pk =
                    (unsigned long long)f2bf(acc[mt][ft][g * 4 + 0]) |
                    ((unsigned long long)f2bf(acc[mt][ft][g * 4 + 1]) << 16) |
                    ((unsigned long long)f2bf(acc[mt][ft][g * 4 + 2]) << 32) |
                    ((unsigned long long)f2bf(acc[mt][ft][g * 4 + 3]) << 48);
                *(unsigned long long*)(Ht + n * NPAD + m0) = pk;
            }
        }
}

// ---------------- f1/f2, pre-scaled by log2e (verified r6) ----------------
__global__ void f12_kern(const unsigned short* __restrict__ Ht, const float* __restrict__ a1,
                         const float* __restrict__ a2, float* __restrict__ f1, float* __restrict__ f2,
                         int fdim) {
    int h = blockIdx.y;
    int i = blockIdx.x * 256 + threadIdx.x;
    if (i >= NPAD) return;
    float s1 = 0.f, s2 = 0.f;
    const unsigned short* base = Ht + (size_t)h * fdim * NPAD + i;
    for (int f = 0; f < fdim; ++f) {
        float v = bf2f(base[(size_t)f * NPAD]);
        s1 = fmaf(v, a1[h * fdim + f], s1);
        s2 = fmaf(v, a2[h * fdim + f], s2);
    }
    f1[(size_t)h * NPAD + i] = s1 * L2E;
    f2[(size_t)h * NPAD + i] = s2 * L2E;
}

// per-head global max -> RA/RB (verified r5/r6)
__global__ void rarb_kern(const float* __restrict__ f1all, const float* __restrict__ f2all,
                          float* __restrict__ RA, float* __restrict__ RB) {
    int h = blockIdx.x;
    __shared__ float red[8];
    const float* f2h = f2all + (size_t)h * NPAD;
    float m = -3.0e38f;
    for (int i = threadIdx.x; i < NN; i += 256) m = fmaxf(m, f2h[i]);
    for (int off = 32; off; off >>= 1) m = fmaxf(m, __shfl_xor(m, off));
    if ((threadIdx.x & 63) == 0) red[threadIdx.x >> 6] = m;
    __syncthreads();
    if (threadIdx.x == 0)
        red[4] = fmaxf(fmaxf(red[0], red[1]), fmaxf(red[2], red[3]));
    __syncthreads();
    float Mh = red[4];
    for (int i = threadIdx.x; i < NPAD; i += 256) {
        float F1 = (i < NN) ? f1all[(size_t)h * NPAD + i] : 0.f;
        float t2 = F1 + Mh;
        float Mi = fmaxf(t2, 0.2f * t2);
        RA[(size_t)h * NPAD + i] = F1 - Mi;
        RB[(size_t)h * NPAD + i] = 0.2f * F1 - Mi;
    }
}

// ---------------- main attention v4: BARRIER-FREE, register-direct B, ones-MFMA dsum ----------------
// grid 376 (1-D): h = bid&7 (head->XCD pin), rowblock = bid>>3 (128 rows, 4 waves x 32).
// No LDS, no __syncthreads: B-fragments read straight from L2 (3MB head slice is L2-resident).
__global__ __launch_bounds__(256) void attn_main(
    const unsigned short* __restrict__ Ht,
    const unsigned long long* __restrict__ mask,
    const float* __restrict__ RA, const float* __restrict__ RB,
    const float* __restrict__ F2,
    unsigned short* __restrict__ x2)
{
    const int bid = blockIdx.x;
    const int h = bid & 7;
    const int rowbase = (bid >> 3) * 128;
    const int w = threadIdx.x >> 6, l = threadIdx.x & 63;
    const int lrow = l & 31, kh = l >> 5;
    const int myrow = rowbase + w * 32 + lrow;
    const bool act = myrow < NN;
    const unsigned short* Hh = Ht + (size_t)h * HID * NPAD;
    const float* F2h = F2 + (size_t)h * NPAD;
    const float ra = RA[(size_t)h * NPAD + myrow], rb = RB[(size_t)h * NPAD + myrow];
    const short8 ones = { (short)0x3F80, (short)0x3F80, (short)0x3F80, (short)0x3F80,
                          (short)0x3F80, (short)0x3F80, (short)0x3F80, (short)0x3F80 };
    f32x16 acc[8];
    f32x16 asum = (f32x16)0.0f;
#pragma unroll
    for (int i = 0; i < 8; ++i) acc[i] = (f32x16)0.0f;

    unsigned long long mw = act ? mask[(size_t)myrow * MSTR] : 0ull;
#pragma unroll 1
    for (int jb = 0; jb < NJB; ++jb) {
        unsigned long long mw_n = (act && jb + 1 < NJB) ? mask[(size_t)myrow * MSTR + jb + 1] : 0ull;
#pragma unroll
        for (int kk = 0; kk < 4; ++kk) {
            // B-fragments straight from global (L2-resident head slice)
            const unsigned short* bbase = Hh + (size_t)jb * 64 + (kk * 2 + kh) * 8;
            short8 bf[8];
#pragma unroll
            for (int ft = 0; ft < 8; ++ft)
                bf[ft] = *(const short8*)(bbase + (size_t)(ft * 32 + lrow) * NPAD);
            unsigned int mbyte = (unsigned int)((mw >> (kk * 16 + kh * 8)) & 0xffull);
            int j0 = jb * 64 + kk * 16 + kh * 8;
            f32x4 fa0 = *(const f32x4*)(F2h + j0);
            f32x4 fa1 = *(const f32x4*)(F2h + j0 + 4);
            float p[8];
#pragma unroll
            for (int e = 0; e < 8; ++e) {
                float fe = (e < 4) ? fa0[e & 3] : fa1[e & 3];
                float pe = exp2f(fmaxf(ra + fe, rb + 0.2f * fe));
                p[e] = (mbyte & (1u << e)) ? pe : 0.f;
            }
            union { unsigned int u[4]; short8 s8; } cv;
#pragma unroll
            for (int q = 0; q < 4; ++q)
                cv.u[q] = __builtin_amdgcn_perm(__float_as_uint(p[2 * q + 1]),
                                                __float_as_uint(p[2 * q]), 0x07060302u);
            __builtin_amdgcn_s_setprio(1);
            asum = __builtin_amdgcn_mfma_f32_32x32x16_bf16(cv.s8, ones, asum, 0, 0, 0);
#pragma unroll
            for (int ft = 0; ft < 8; ++ft)
                acc[ft] = __builtin_amdgcn_mfma_f32_32x32x16_bf16(cv.s8, bf[ft], acc[ft], 0, 0, 0);
            __builtin_amdgcn_s_setprio(0);
        }
        mw = mw_n;
    }

    // denominators live in matching register slots of asum (ones-column trick): no shuffles
    float dinv[16];
#pragma unroll
    for (int t = 0; t < 16; ++t)
        dinv[t] = (asum[t] > 0.f) ? (1.0f / asum[t]) : 0.f;

#pragma unroll
    for (int ft = 0; ft < 8; ++ft)
#pragma unroll
        for (int g = 0; g < 4; ++g)
#pragma unroll
            for (int rr = 0; rr < 4; ++rr) {
                int grow = rowbase + w * 32 + (g << 3) + (kh << 2) + rr;
                if (grow < NN) {
                    float v = acc[ft][g * 4 + rr] * dinv[g * 4 + rr];
                    v = (v > 0.f) ? v : (__expf(v) - 1.f);
                    x2[(size_t)grow * FTOT + h * HID + ft * 32 + lrow] = f2bf(v);
                }
            }
}

// ---------------- GEMM2: split-K x8 -> f32 partials (verified r5) ----------------
__global__ __launch_bounds__(256, 2) void gemm_hc(const unsigned short* __restrict__ A,
                                                  const unsigned short* __restrict__ B,
                                                  float* __restrict__ pk) {
    int w = threadIdx.x >> 6, l = threadIdx.x & 63;
    int lrow = l & 31, kh = l >> 5;
    int q = blockIdx.y;
    int nbase = blockIdx.x * 128 + w * 32;
    int brow = nbase + lrow; if (brow > NN - 1) brow = NN - 1;
    f32x16 acc = (f32x16)0.0f;
    const short8* ap = (const short8*)(A + (size_t)lrow * FTOT + q * 256 + kh * 8);
    const short8* bp = (const short8*)(B + (size_t)brow * FTOT + q * 256 + kh * 8);
#pragma unroll
    for (int kk = 0; kk < 16; ++kk) {
        short8 af = ap[kk * 2];
        short8 bf = bp[kk * 2];
        acc = __builtin_amdgcn_mfma_f32_32x32x16_bf16(af, bf, acc, 0, 0, 0);
    }
    int i = nbase + lrow;
#pragma unroll
    for (int g = 0; g < 4; ++g) {
        int c0 = (g << 3) + (kh << 2);
#pragma unroll
        for (int r = 0; r < 4; ++r)
            pk[((size_t)q * NC + c0 + r) * NPAD + i] = acc[g * 4 + r];
    }
}

__global__ void merge_hc(const float* __restrict__ pk, unsigned short* __restrict__ hct) {
    int i = blockIdx.x * 256 + threadIdx.x;
    int c = blockIdx.y;
    if (i >= NPAD) return;
    float s = 0.f;
#pragma unroll
    for (int q = 0; q < 8; ++q) s += pk[((size_t)q * NC + c) * NPAD + i];
    hct[(size_t)c * NPAD + i] = f2bf(s);
}

// ---------------- classifier attention v2: barrier-free, j-split 4, ones-MFMA dsum ----------------
__global__ __launch_bounds__(256) void cls_part(
    const unsigned short* __restrict__ hctb,
    const unsigned long long* __restrict__ mask,
    const float* __restrict__ RAc, const float* __restrict__ RBc,
    const float* __restrict__ F2c,
    float* __restrict__ pacc, float* __restrict__ pdsum)
{
    const int w = threadIdx.x >> 6, l = threadIdx.x & 63;
    const int lrow = l & 31, kh = l >> 5;
    const int q = blockIdx.y;
    const int rowbase = blockIdx.x * 128;
    const int myrow = rowbase + w * 32 + lrow;
    const bool act = myrow < NN;
    float ra = RAc[myrow], rb = RBc[myrow];
    const int JB0 = q * 24, JB1 = (JB0 + 24 < NJB) ? JB0 + 24 : NJB;
    const short8 ones = { (short)0x3F80, (short)0x3F80, (short)0x3F80, (short)0x3F80,
                          (short)0x3F80, (short)0x3F80, (short)0x3F80, (short)0x3F80 };
    f32x16 acc = (f32x16)0.0f;
    f32x16 asum = (f32x16)0.0f;

#pragma unroll 1
    for (int jb = JB0; jb < JB1; ++jb) {
        unsigned long long mword = act ? mask[(size_t)myrow * MSTR + jb] : 0ull;
#pragma unroll
        for (int kk = 0; kk < 4; ++kk) {
            short8 bfrag = *(const short8*)(hctb + (size_t)lrow * NPAD + jb * 64 + (kk * 2 + kh) * 8);
            unsigned int mbyte = (unsigned int)((mword >> (kk * 16 + kh * 8)) & 0xffull);
            int j0 = jb * 64 + kk * 16 + kh * 8;
            f32x4 fa0 = *(const f32x4*)(F2c + j0);
            f32x4 fa1 = *(const f32x4*)(F2c + j0 + 4);
            float p[8];
#pragma unroll
            for (int e = 0; e < 8; ++e) {
                float fe = (e < 4) ? fa0[e & 3] : fa1[e & 3];
                float pe = exp2f(fmaxf(ra + fe, rb + 0.2f * fe));
                p[e] = (mbyte & (1u << e)) ? pe : 0.f;
            }
            union { unsigned int u[4]; short8 s8; } cv;
#pragma unroll
            for (int t = 0; t < 4; ++t)
                cv.u[t] = __builtin_amdgcn_perm(__float_as_uint(p[2 * t + 1]),
                                                __float_as_uint(p[2 * t]), 0x07060302u);
            asum = __builtin_amdgcn_mfma_f32_32x32x16_bf16(cv.s8, ones, asum, 0, 0, 0);
            acc = __builtin_amdgcn_mfma_f32_32x32x16_bf16(cv.s8, bfrag, acc, 0, 0, 0);
        }
    }
#pragma unroll
    for (int g = 0; g < 4; ++g)
#pragma unroll
        for (int rr = 0; rr < 4; ++rr) {
            int i = rowbase + w * 32 + (g << 3) + (kh << 2) + rr;
            pacc[((size_t)q * NPAD + i) * NC + lrow] = acc[g * 4 + rr];
            if (lrow == 0) pdsum[(size_t)q * NPAD + i] = asum[g * 4 + rr];
        }
}

__global__ void cls_merge(const float* __restrict__ pacc, const float* __restrict__ pdsum,
                          float* __restrict__ outp) {
    int i = blockIdx.x * 8 + (threadIdx.x >> 5);
    int c = threadIdx.x & 31;
    if (i >= NN) return;
    float num = 0.f, den = 0.f;
#pragma unroll
    for (int q = 0; q < 4; ++q) {
        num += pacc[((size_t)q * NPAD + i) * NC + c];
        den += pdsum[(size_t)q * NPAD + i];
    }
    outp[(size_t)i * NC + c] = (den > 0.f) ? num / den : 0.f;
}

// ---------------- launcher ----------------
extern "C" void kernel_launch(void* const* d_in, const int* in_sizes, int n_in,
                              void* d_out, int out_size, void* d_ws, size_t ws_size,
                              hipStream_t stream) {
    const float* features = (const float*)d_in[0];
    const int*   adj      = (const int*)d_in[1];
    const float* W0       = (const float*)d_in[2];
    const float* a10      = (const float*)d_in[3];
    const float* a20      = (const float*)d_in[4];
    const float* Wc       = (const float*)d_in[5];
    const float* a1c      = (const float*)d_in[6];
    const float* a2c      = (const float*)d_in[7];
    float* out = (float*)d_out;

    char* p = (char*)d_ws;
    auto alloc = [&](size_t bytes) { char* r = p; p += (bytes + 255) & ~(size_t)255; return r; };
    unsigned long long* mask = (unsigned long long*)alloc((size_t)NN * MSTR * 8);
    unsigned short* Xbf = (unsigned short*)alloc((size_t)NN * DF * 2);
    unsigned short* Wt  = (unsigned short*)alloc((size_t)FTOT * DF * 2);
    unsigned short* Ht  = (unsigned short*)alloc((size_t)FTOT * NPAD * 2);
    unsigned short* x2  = (unsigned short*)alloc((size_t)NN * FTOT * 2);
    unsigned short* Wct = (unsigned short*)alloc((size_t)NC * FTOT * 2);
    unsigned short* hct = (unsigned short*)alloc((size_t)NC * NPAD * 2);
    float* f1  = (float*)alloc((size_t)NH * NPAD * 4);
    float* f2  = (float*)alloc((size_t)NH * NPAD * 4);
    float* RA  = (float*)alloc((size_t)NH * NPAD * 4);
    float* RB  = (float*)alloc((size_t)NH * NPAD * 4);
    float* f1c  = (float*)alloc((size_t)NPAD * 4);
    float* f2c  = (float*)alloc((size_t)NPAD * 4);
    float* RAc  = (float*)alloc((size_t)NPAD * 4);
    float* RBc  = (float*)alloc((size_t)NPAD * 4);
    // overlays on dead Xbf+Wt (8.26 MB): pkhc 6.16 MB (gemm_hc), then pacc 3.08 MB + pdsum 96 KB (cls)
    float* pkhc  = (float*)Xbf;
    float* pacc  = (float*)Xbf;
    float* pdsum = pacc + (size_t)4 * NPAD * NC;

    pack_bits<<<dim3(3, NN), 256, 0, stream>>>(adj, (unsigned char*)mask);
    cast_x4<<<(NN * DF / 4 + 255) / 256, 256, 0, stream>>>(features, Xbf, NN * DF / 4);
    wt_pack<<<FTOT, 256, 0, stream>>>(W0, Wt);
    wct_pack<<<NC, 256, 0, stream>>>(Wc, Wct);

    gemm_h<<<dim3(NPAD / 128, FTOT / 128), 256, 0, stream>>>(Xbf, Wt, Ht);
    f12_kern<<<dim3((NPAD + 255) / 256, NH), 256, 0, stream>>>(Ht, a10, a20, f1, f2, HID);
    rarb_kern<<<NH, 256, 0, stream>>>(f1, f2, RA, RB);

    attn_main<<<dim3(47 * NH), 256, 0, stream>>>(Ht, mask, RA, RB, f2, x2);

    gemm_hc<<<dim3(NPAD / 128, 8), 256, 0, stream>>>(Wct, x2, pkhc);
    merge_hc<<<dim3((NPAD + 255) / 256, NC), 256, 0, stream>>>(pkhc, hct);
    f12_kern<<<dim3((NPAD + 255) / 256, 1), 256, 0, stream>>>(hct, a1c, a2c, f1c, f2c, NC);
    rarb_kern<<<1, 256, 0, stream>>>(f1c, f2c, RAc, RBc);

    cls_part<<<dim3(47, 4), 256, 0, stream>>>(hct, mask, RAc, RBc, f2c, pacc, pdsum);
    cls_merge<<<750, 256, 0, stream>>>(pacc, pdsum, out);
}

// Round 8
// 522.473 us; speedup vs baseline: 1.8973x; 1.8973x over previous
//
#include <hip/hip_runtime.h>
#include <hip/hip_bf16.h>

#define NN 6000
#define NPAD 6016      // 94*64
#define DF 512
#define HID 256
#define NH 8
#define NC 32
#define FTOT 2048
#define MSTR 96        // u64 words per mask row
#define NJB (NPAD / 64)
#define L2E 1.4426950408889634f

using short8 = __attribute__((ext_vector_type(8))) short;
using f32x16 = __attribute__((ext_vector_type(16))) float;
using f32x4  = __attribute__((ext_vector_type(4))) float;

__device__ __forceinline__ unsigned short f2bf(float f) {
    unsigned int u = __float_as_uint(f);
    return (unsigned short)((u + 0x7fffu + ((u >> 16) & 1u)) >> 16);
}
__device__ __forceinline__ float bf2f(unsigned short s) {
    return __uint_as_float(((unsigned int)s) << 16);
}
// async global->LDS, 16B per lane
__device__ __forceinline__ void gl16(const void* g, void* l) {
    __builtin_amdgcn_global_load_lds(
        (const __attribute__((address_space(1))) unsigned int*)g,
        (__attribute__((address_space(3))) unsigned int*)l, 16, 0, 0);
}

// ---------------- prep kernels (verified r3/r4) ----------------

__global__ void pack_bits(const int* __restrict__ adj, unsigned char* __restrict__ maskb) {
    int row = blockIdx.y;
    int b = blockIdx.x * 256 + threadIdx.x;     // byte index 0..767
    if (b >= 768) return;
    int j0 = b * 8;
    unsigned int v = 0;
    if (j0 + 7 < NN) {
        const int4* p = (const int4*)(adj + (size_t)row * NN + j0);
        int4 a = p[0], c = p[1];
        v = (unsigned)((a.x>0) | ((a.y>0)<<1) | ((a.z>0)<<2) | ((a.w>0)<<3)
          | ((c.x>0)<<4) | ((c.y>0)<<5) | ((c.z>0)<<6) | ((c.w>0)<<7));
    }
    maskb[(size_t)row * 768 + b] = (unsigned char)v;
}

__global__ void cast_x4(const float* __restrict__ x, unsigned short* __restrict__ xb, int n4) {
    int i = blockIdx.x * 256 + threadIdx.x;
    if (i >= n4) return;
    float4 v = ((const float4*)x)[i];
    unsigned long long pk = (unsigned long long)f2bf(v.x)
        | ((unsigned long long)f2bf(v.y) << 16)
        | ((unsigned long long)f2bf(v.z) << 32)
        | ((unsigned long long)f2bf(v.w) << 48);
    ((unsigned long long*)xb)[i] = pk;
}

__global__ void wt_pack(const float* __restrict__ W0, unsigned short* __restrict__ Wt) {
    int fp = blockIdx.x;                 // h*256+f
    int h = fp >> 8, f = fp & 255;
    for (int k = threadIdx.x; k < DF; k += 256)
        Wt[(size_t)fp * DF + k] = f2bf(W0[(((size_t)h * DF + k) << 8) | f]);
}

__global__ void wct_pack(const float* __restrict__ Wc, unsigned short* __restrict__ Wct) {
    int c = blockIdx.x;
    for (int k = threadIdx.x; k < FTOT; k += 256)
        Wct[(size_t)c * FTOT + k] = f2bf(Wc[(size_t)k * NC + c]);
}

// ---------------- GEMM1 (verified r3): Ht[f][i] = sum_k X[i][k] W[k][f] ----------------
__global__ __launch_bounds__(256, 2) void gemm_h(const unsigned short* __restrict__ A,
                                                 const unsigned short* __restrict__ B,
                                                 unsigned short* __restrict__ Ht) {
    __shared__ __align__(16) unsigned short As[128 * 64];
    __shared__ __align__(16) unsigned short Bs[128 * 64];
    const int w = threadIdx.x >> 6, l = threadIdx.x & 63;
    const int lrow = l & 31, kh = l >> 5;
    const int wm = w >> 1, wn = w & 1;
    const int mbase = blockIdx.x * 128, nbase = blockIdx.y * 128;
    const int srcc = (l & 7) ^ (l >> 3);
    f32x16 acc[2][2];
#pragma unroll
    for (int i = 0; i < 2; ++i)
#pragma unroll
        for (int j = 0; j < 2; ++j) acc[i][j] = (f32x16)0.0f;

#pragma unroll 1
    for (int kb = 0; kb < DF / 64; ++kb) {
        __syncthreads();
#pragma unroll
        for (int q = 0; q < 4; ++q) {
            int c = q * 4 + w;
            int r = c * 8 + (l >> 3);
            int arow = mbase + r; if (arow > NN - 1) arow = NN - 1;
            gl16(A + (size_t)arow * DF + kb * 64 + srcc * 8, (char*)As + c * 1024);
            gl16(B + (size_t)(nbase + r) * DF + kb * 64 + srcc * 8, (char*)Bs + c * 1024);
        }
        __syncthreads();
#pragma unroll
        for (int kk = 0; kk < 4; ++kk) {
            short8 av[2], bv[2];
#pragma unroll
            for (int mt = 0; mt < 2; ++mt) {
                int r = wm * 64 + mt * 32 + lrow;
                av[mt] = *(const short8*)((const char*)As + r * 128 + ((((kk << 1) | kh) ^ (r & 7)) << 4));
            }
#pragma unroll
            for (int ft = 0; ft < 2; ++ft) {
                int r = wn * 64 + ft * 32 + lrow;
                bv[ft] = *(const short8*)((const char*)Bs + r * 128 + ((((kk << 1) | kh) ^ (r & 7)) << 4));
            }
#pragma unroll
            for (int mt = 0; mt < 2; ++mt)
#pragma unroll
                for (int ft = 0; ft < 2; ++ft)
                    acc[mt][ft] = __builtin_amdgcn_mfma_f32_32x32x16_bf16(av[mt], bv[ft], acc[mt][ft], 0, 0, 0);
        }
    }
#pragma unroll
    for (int mt = 0; mt < 2; ++mt)
#pragma unroll
        for (int ft = 0; ft < 2; ++ft) {
            size_t n = nbase + wn * 64 + ft * 32 + lrow;
#pragma unroll
            for (int g = 0; g < 4; ++g) {
                int m0 = mbase + wm * 64 + mt * 32 + (g << 3) + (kh << 2);
                unsigned long long pk =
                    (unsigned long long)f2bf(acc[mt][ft][g * 4 + 0]) |
                    ((unsigned long long)f2bf(acc[mt][ft][g * 4 + 1]) << 16) |
                    ((unsigned long long)f2bf(acc[mt][ft][g * 4 + 2]) << 32) |
                    ((unsigned long long)f2bf(acc[mt][ft][g * 4 + 3]) << 48);
                *(unsigned long long*)(Ht + n * NPAD + m0) = pk;
            }
        }
}

// ---------------- f1/f2, pre-scaled by log2e (verified r6) ----------------
__global__ void f12_kern(const unsigned short* __restrict__ Ht, const float* __restrict__ a1,
                         const float* __restrict__ a2, float* __restrict__ f1, float* __restrict__ f2,
                         int fdim) {
    int h = blockIdx.y;
    int i = blockIdx.x * 256 + threadIdx.x;
    if (i >= NPAD) return;
    float s1 = 0.f, s2 = 0.f;
    const unsigned short* base = Ht + (size_t)h * fdim * NPAD + i;
    for (int f = 0; f < fdim; ++f) {
        float v = bf2f(base[(size_t)f * NPAD]);
        s1 = fmaf(v, a1[h * fdim + f], s1);
        s2 = fmaf(v, a2[h * fdim + f], s2);
    }
    f1[(size_t)h * NPAD + i] = s1 * L2E;
    f2[(size_t)h * NPAD + i] = s2 * L2E;
}

// per-head global max -> RA/RB (verified r5/r6)
__global__ void rarb_kern(const float* __restrict__ f1all, const float* __restrict__ f2all,
                          float* __restrict__ RA, float* __restrict__ RB) {
    int h = blockIdx.x;
    __shared__ float red[8];
    const float* f2h = f2all + (size_t)h * NPAD;
    float m = -3.0e38f;
    for (int i = threadIdx.x; i < NN; i += 256) m = fmaxf(m, f2h[i]);
    for (int off = 32; off; off >>= 1) m = fmaxf(m, __shfl_xor(m, off));
    if ((threadIdx.x & 63) == 0) red[threadIdx.x >> 6] = m;
    __syncthreads();
    if (threadIdx.x == 0)
        red[4] = fmaxf(fmaxf(red[0], red[1]), fmaxf(red[2], red[3]));
    __syncthreads();
    float Mh = red[4];
    for (int i = threadIdx.x; i < NPAD; i += 256) {
        float F1 = (i < NN) ? f1all[(size_t)h * NPAD + i] : 0.f;
        float t2 = F1 + Mh;
        float Mi = fmaxf(t2, 0.2f * t2);
        RA[(size_t)h * NPAD + i] = F1 - Mi;
        RB[(size_t)h * NPAD + i] = 0.2f * F1 - Mi;
    }
}

// ---------------- main attention v5: triple-buffer LDS, counted vmcnt, raw s_barrier ----------------
// grid 752: h = bid&7 (head->XCD pin), fh = (bid>>3)&1 (feature half), rowblk = bid>>4.
// Per jb: STAGE(t+1) -> s_waitcnt vmcnt(4) -> s_barrier (non-draining) -> compute(t).
// Triple buffer: writer (t+1) vs readers {t-1,t} distinct mod 3. No vmcnt(0) drain anywhere.
__global__ __launch_bounds__(256, 3) void attn_main(
    const unsigned short* __restrict__ Ht,
    const unsigned long long* __restrict__ mask,
    const float* __restrict__ RA, const float* __restrict__ RB,
    const float* __restrict__ F2,
    unsigned short* __restrict__ x2)
{
    __shared__ __align__(16) unsigned short htile[3 * 128 * 64];   // 48 KB, swizzled [128][64] x3
    const int bid = blockIdx.x;
    const int h = bid & 7;
    const int fh = (bid >> 3) & 1;
    const int rowbase = (bid >> 4) * 128;
    const int w = threadIdx.x >> 6, l = threadIdx.x & 63;
    const int lrow = l & 31, kh = l >> 5;
    const int myrow = rowbase + w * 32 + lrow;
    const bool act = myrow < NN;
    const unsigned short* Hh = Ht + ((size_t)h * HID + fh * 128) * NPAD;
    const float* F2h = F2 + (size_t)h * NPAD;
    const float ra = RA[(size_t)h * NPAD + myrow], rb = RB[(size_t)h * NPAD + myrow];
    const int srcc = (l & 7) ^ (l >> 3);
    const short8 ones = { (short)0x3F80, (short)0x3F80, (short)0x3F80, (short)0x3F80,
                          (short)0x3F80, (short)0x3F80, (short)0x3F80, (short)0x3F80 };
    f32x16 acc[4];
    f32x16 asum = (f32x16)0.0f;
#pragma unroll
    for (int i = 0; i < 4; ++i) acc[i] = (f32x16)0.0f;

    auto STAGE = [&](int buf, int jb) {
#pragma unroll
        for (int q = 0; q < 4; ++q) {
            int c = q * 4 + w;                   // chunk 0..15
            int f = c * 8 + (l >> 3);            // tile row 0..127
            gl16(Hh + (size_t)f * NPAD + jb * 64 + srcc * 8, (char*)htile + buf * 16384 + c * 1024);
        }
    };

    STAGE(0, 0);
#pragma unroll 1
    for (int jb = 0; jb < NJB; ++jb) {
        if (jb + 1 < NJB) STAGE((jb + 1) % 3, jb + 1);     // depth-1 prefetch (4 gl16, static)
        // own tile-jb loads retired (younger >= 4 always); prefetch stays in flight
        asm volatile("s_waitcnt vmcnt(4)" ::: "memory");
        __builtin_amdgcn_sched_barrier(0);
        __builtin_amdgcn_s_barrier();                      // publish tile jb (non-draining)
        __builtin_amdgcn_sched_barrier(0);
        const char* tb = (const char*)htile + (jb % 3) * 16384;
        unsigned long long mw = act ? mask[(size_t)myrow * MSTR + jb] : 0ull;
#pragma unroll
        for (int kk = 0; kk < 4; ++kk) {
            unsigned int mbyte = (unsigned int)((mw >> (kk * 16 + kh * 8)) & 0xffull);
            int j0 = jb * 64 + kk * 16 + kh * 8;
            f32x4 fa0 = *(const f32x4*)(F2h + j0);
            f32x4 fa1 = *(const f32x4*)(F2h + j0 + 4);
            float p[8];
#pragma unroll
            for (int e = 0; e < 8; ++e) {
                float fe = (e < 4) ? fa0[e & 3] : fa1[e & 3];
                float pe = exp2f(fmaxf(ra + fe, rb + 0.2f * fe));
                p[e] = (mbyte & (1u << e)) ? pe : 0.f;
            }
            union { unsigned int u[4]; short8 s8; } cv;
#pragma unroll
            for (int q = 0; q < 4; ++q)
                cv.u[q] = __builtin_amdgcn_perm(__float_as_uint(p[2 * q + 1]),
                                                __float_as_uint(p[2 * q]), 0x07060302u);
            __builtin_amdgcn_s_setprio(1);
            asum = __builtin_amdgcn_mfma_f32_32x32x16_bf16(cv.s8, ones, asum, 0, 0, 0);
#pragma unroll
            for (int ft = 0; ft < 4; ++ft) {
                int fr = ft * 32 + lrow;
                short8 bfrag = *(const short8*)(tb + fr * 128 + (((kk * 2 + kh) * 16) ^ ((fr & 7) << 4)));
                acc[ft] = __builtin_amdgcn_mfma_f32_32x32x16_bf16(cv.s8, bfrag, acc[ft], 0, 0, 0);
            }
            __builtin_amdgcn_s_setprio(0);
        }
    }

    // denominators in matching register slots (ones-column trick, r7-verified)
    float dinv[16];
#pragma unroll
    for (int t = 0; t < 16; ++t)
        dinv[t] = (asum[t] > 0.f) ? (1.0f / asum[t]) : 0.f;

#pragma unroll
    for (int ft = 0; ft < 4; ++ft)
#pragma unroll
        for (int g = 0; g < 4; ++g)
#pragma unroll
            for (int rr = 0; rr < 4; ++rr) {
                int grow = rowbase + w * 32 + (g << 3) + (kh << 2) + rr;
                if (grow < NN) {
                    float v = acc[ft][g * 4 + rr] * dinv[g * 4 + rr];
                    v = (v > 0.f) ? v : (__expf(v) - 1.f);
                    x2[(size_t)grow * FTOT + h * HID + fh * 128 + ft * 32 + lrow] = f2bf(v);
                }
            }
}

// ---------------- GEMM2: split-K x8 -> f32 partials (verified r5) ----------------
__global__ __launch_bounds__(256, 2) void gemm_hc(const unsigned short* __restrict__ A,
                                                  const unsigned short* __restrict__ B,
                                                  float* __restrict__ pk) {
    int w = threadIdx.x >> 6, l = threadIdx.x & 63;
    int lrow = l & 31, kh = l >> 5;
    int q = blockIdx.y;
    int nbase = blockIdx.x * 128 + w * 32;
    int brow = nbase + lrow; if (brow > NN - 1) brow = NN - 1;
    f32x16 acc = (f32x16)0.0f;
    const short8* ap = (const short8*)(A + (size_t)lrow * FTOT + q * 256 + kh * 8);
    const short8* bp = (const short8*)(B + (size_t)brow * FTOT + q * 256 + kh * 8);
#pragma unroll
    for (int kk = 0; kk < 16; ++kk) {
        short8 af = ap[kk * 2];
        short8 bf = bp[kk * 2];
        acc = __builtin_amdgcn_mfma_f32_32x32x16_bf16(af, bf, acc, 0, 0, 0);
    }
    int i = nbase + lrow;
#pragma unroll
    for (int g = 0; g < 4; ++g) {
        int c0 = (g << 3) + (kh << 2);
#pragma unroll
        for (int r = 0; r < 4; ++r)
            pk[((size_t)q * NC + c0 + r) * NPAD + i] = acc[g * 4 + r];
    }
}

__global__ void merge_hc(const float* __restrict__ pk, unsigned short* __restrict__ hct) {
    int i = blockIdx.x * 256 + threadIdx.x;
    int c = blockIdx.y;
    if (i >= NPAD) return;
    float s = 0.f;
#pragma unroll
    for (int q = 0; q < 8; ++q) s += pk[((size_t)q * NC + c) * NPAD + i];
    hct[(size_t)c * NPAD + i] = f2bf(s);
}

// ---------------- classifier attention (verified r7): barrier-free, j-split 4, ones dsum ----------------
__global__ __launch_bounds__(256) void cls_part(
    const unsigned short* __restrict__ hctb,
    const unsigned long long* __restrict__ mask,
    const float* __restrict__ RAc, const float* __restrict__ RBc,
    const float* __restrict__ F2c,
    float* __restrict__ pacc, float* __restrict__ pdsum)
{
    const int w = threadIdx.x >> 6, l = threadIdx.x & 63;
    const int lrow = l & 31, kh = l >> 5;
    const int q = blockIdx.y;
    const int rowbase = blockIdx.x * 128;
    const int myrow = rowbase + w * 32 + lrow;
    const bool act = myrow < NN;
    float ra = RAc[myrow], rb = RBc[myrow];
    const int JB0 = q * 24, JB1 = (JB0 + 24 < NJB) ? JB0 + 24 : NJB;
    const short8 ones = { (short)0x3F80, (short)0x3F80, (short)0x3F80, (short)0x3F80,
                          (short)0x3F80, (short)0x3F80, (short)0x3F80, (short)0x3F80 };
    f32x16 acc = (f32x16)0.0f;
    f32x16 asum = (f32x16)0.0f;

#pragma unroll 1
    for (int jb = JB0; jb < JB1; ++jb) {
        unsigned long long mword = act ? mask[(size_t)myrow * MSTR + jb] : 0ull;
#pragma unroll
        for (int kk = 0; kk < 4; ++kk) {
            short8 bfrag = *(const short8*)(hctb + (size_t)lrow * NPAD + jb * 64 + (kk * 2 + kh) * 8);
            unsigned int mbyte = (unsigned int)((mword >> (kk * 16 + kh * 8)) & 0xffull);
            int j0 = jb * 64 + kk * 16 + kh * 8;
            f32x4 fa0 = *(const f32x4*)(F2c + j0);
            f32x4 fa1 = *(const f32x4*)(F2c + j0 + 4);
            float p[8];
#pragma unroll
            for (int e = 0; e < 8; ++e) {
                float fe = (e < 4) ? fa0[e & 3] : fa1[e & 3];
                float pe = exp2f(fmaxf(ra + fe, rb + 0.2f * fe));
                p[e] = (mbyte & (1u << e)) ? pe : 0.f;
            }
            union { unsigned int u[4]; short8 s8; } cv;
#pragma unroll
            for (int t = 0; t < 4; ++t)
                cv.u[t] = __builtin_amdgcn_perm(__float_as_uint(p[2 * t + 1]),
                                                __float_as_uint(p[2 * t]), 0x07060302u);
            asum = __builtin_amdgcn_mfma_f32_32x32x16_bf16(cv.s8, ones, asum, 0, 0, 0);
            acc = __builtin_amdgcn_mfma_f32_32x32x16_bf16(cv.s8, bfrag, acc, 0, 0, 0);
        }
    }
#pragma unroll
    for (int g = 0; g < 4; ++g)
#pragma unroll
        for (int rr = 0; rr < 4; ++rr) {
            int i = rowbase + w * 32 + (g << 3) + (kh << 2) + rr;
            pacc[((size_t)q * NPAD + i) * NC + lrow] = acc[g * 4 + rr];
            if (lrow == 0) pdsum[(size_t)q * NPAD + i] = asum[g * 4 + rr];
        }
}

__global__ void cls_merge(const float* __restrict__ pacc, const float* __restrict__ pdsum,
                          float* __restrict__ outp) {
    int i = blockIdx.x * 8 + (threadIdx.x >> 5);
    int c = threadIdx.x & 31;
    if (i >= NN) return;
    float num = 0.f, den = 0.f;
#pragma unroll
    for (int q = 0; q < 4; ++q) {
        num += pacc[((size_t)q * NPAD + i) * NC + c];
        den += pdsum[(size_t)q * NPAD + i];
    }
    outp[(size_t)i * NC + c] = (den > 0.f) ? num / den : 0.f;
}

// ---------------- launcher ----------------
extern "C" void kernel_launch(void* const* d_in, const int* in_sizes, int n_in,
                              void* d_out, int out_size, void* d_ws, size_t ws_size,
                              hipStream_t stream) {
    const float* features = (const float*)d_in[0];
    const int*   adj      = (const int*)d_in[1];
    const float* W0       = (const float*)d_in[2];
    const float* a10      = (const float*)d_in[3];
    const float* a20      = (const float*)d_in[4];
    const float* Wc       = (const float*)d_in[5];
    const float* a1c      = (const float*)d_in[6];
    const float* a2c      = (const float*)d_in[7];
    float* out = (float*)d_out;

    char* p = (char*)d_ws;
    auto alloc = [&](size_t bytes) { char* r = p; p += (bytes + 255) & ~(size_t)255; return r; };
    unsigned long long* mask = (unsigned long long*)alloc((size_t)NN * MSTR * 8);
    unsigned short* Xbf = (unsigned short*)alloc((size_t)NN * DF * 2);
    unsigned short* Wt  = (unsigned short*)alloc((size_t)FTOT * DF * 2);
    unsigned short* Ht  = (unsigned short*)alloc((size_t)FTOT * NPAD * 2);
    unsigned short* x2  = (unsigned short*)alloc((size_t)NN * FTOT * 2);
    unsigned short* Wct = (unsigned short*)alloc((size_t)NC * FTOT * 2);
    unsigned short* hct = (unsigned short*)alloc((size_t)NC * NPAD * 2);
    float* f1  = (float*)alloc((size_t)NH * NPAD * 4);
    float* f2  = (float*)alloc((size_t)NH * NPAD * 4);
    float* RA  = (float*)alloc((size_t)NH * NPAD * 4);
    float* RB  = (float*)alloc((size_t)NH * NPAD * 4);
    float* f1c  = (float*)alloc((size_t)NPAD * 4);
    float* f2c  = (float*)alloc((size_t)NPAD * 4);
    float* RAc  = (float*)alloc((size_t)NPAD * 4);
    float* RBc  = (float*)alloc((size_t)NPAD * 4);
    // overlays on dead Xbf+Wt (8.26 MB): pkhc 6.16 MB (gemm_hc), then pacc 3.08 MB + pdsum 96 KB (cls)
    float* pkhc  = (float*)Xbf;
    float* pacc  = (float*)Xbf;
    float* pdsum = pacc + (size_t)4 * NPAD * NC;

    pack_bits<<<dim3(3, NN), 256, 0, stream>>>(adj, (unsigned char*)mask);
    cast_x4<<<(NN * DF / 4 + 255) / 256, 256, 0, stream>>>(features, Xbf, NN * DF / 4);
    wt_pack<<<FTOT, 256, 0, stream>>>(W0, Wt);
    wct_pack<<<NC, 256, 0, stream>>>(Wc, Wct);

    gemm_h<<<dim3(NPAD / 128, FTOT / 128), 256, 0, stream>>>(Xbf, Wt, Ht);
    f12_kern<<<dim3((NPAD + 255) / 256, NH), 256, 0, stream>>>(Ht, a10, a20, f1, f2, HID);
    rarb_kern<<<NH, 256, 0, stream>>>(f1, f2, RA, RB);

    attn_main<<<dim3(47 * 2 * NH), 256, 0, stream>>>(Ht, mask, RA, RB, f2, x2);

    gemm_hc<<<dim3(NPAD / 128, 8), 256, 0, stream>>>(Wct, x2, pkhc);
    merge_hc<<<dim3((NPAD + 255) / 256, NC), 256, 0, stream>>>(pkhc, hct);
    f12_kern<<<dim3((NPAD + 255) / 256, 1), 256, 0, stream>>>(hct, a1c, a2c, f1c, f2c, NC);
    rarb_kern<<<1, 256, 0, stream>>>(f1c, f2c, RAc, RBc);

    cls_part<<<dim3(47, 4), 256, 0, stream>>>(hct, mask, RAc, RBc, f2c, pacc, pdsum);
    cls_merge<<<750, 256, 0, stream>>>(pacc, pdsum, out);
}